// Round 4
// baseline (608.715 us; speedup 1.0000x reference)
//
#include <hip/hip_runtime.h>

#define N_NODES 100000
#define N_EDGES 1250000
#define N_GRAPHS 64
#define F_INN 29
#define HD 64
#define NT 6
#define GT 4
#define NLAYERS 4

// ---------------- CSR construction ----------------

__global__ void count_edges(const int* __restrict__ col, int* __restrict__ cnt, int E) {
    int e = blockIdx.x * blockDim.x + threadIdx.x;
    if (e < E) atomicAdd(&cnt[col[e]], 1);
}

__global__ void compute_dis(const int* __restrict__ cnt, float* __restrict__ dis, int n) {
    int i = blockIdx.x * blockDim.x + threadIdx.x;
    if (i < n) dis[i] = rsqrtf((float)(cnt[i] + 1));  // +1 self loop; always > 0
}

// exclusive scan, 3-kernel hierarchy. scan1: 1024 elems/block (4/thread, block=256)
__global__ void scan1(const int* __restrict__ in, int* __restrict__ out,
                      int* __restrict__ bsums, int n) {
    __shared__ int wsum[4];
    int tid = threadIdx.x;
    int base = blockIdx.x * 1024 + tid * 4;
    int v0 = (base + 0 < n) ? in[base + 0] : 0;
    int v1 = (base + 1 < n) ? in[base + 1] : 0;
    int v2 = (base + 2 < n) ? in[base + 2] : 0;
    int v3 = (base + 3 < n) ? in[base + 3] : 0;
    int tsum = v0 + v1 + v2 + v3;
    int incl = tsum;
    int lane = tid & 63;
    #pragma unroll
    for (int off = 1; off < 64; off <<= 1) {
        int t = __shfl_up(incl, (unsigned)off, 64);
        if (lane >= off) incl += t;
    }
    if (lane == 63) wsum[tid >> 6] = incl;
    __syncthreads();
    int woff = 0;
    for (int w = 0; w < (tid >> 6); ++w) woff += wsum[w];
    int run = woff + incl - tsum;  // exclusive prefix of this thread's first elem
    if (base + 0 < n) out[base + 0] = run; run += v0;
    if (base + 1 < n) out[base + 1] = run; run += v1;
    if (base + 2 < n) out[base + 2] = run; run += v2;
    if (base + 3 < n) out[base + 3] = run;
    if (tid == 255) bsums[blockIdx.x] = woff + incl;  // block total
}

__global__ void scan2(int* __restrict__ bsums, int nb) {
    __shared__ int s[256];
    int tid = threadIdx.x;
    int v = (tid < nb) ? bsums[tid] : 0;
    s[tid] = v;
    __syncthreads();
    #pragma unroll
    for (int off = 1; off < 256; off <<= 1) {
        int t = (tid >= off) ? s[tid - off] : 0;
        __syncthreads();
        s[tid] += t;
        __syncthreads();
    }
    if (tid < nb) bsums[tid] = s[tid] - v;  // exclusive, in place
}

__global__ void scan3(int* __restrict__ out, const int* __restrict__ bsums, int n) {
    int i = blockIdx.x * blockDim.x + threadIdx.x;
    if (i < n) out[i] += bsums[i >> 10];
}

// packed edge record: {src index (bit-cast), dis[src]}
__global__ void fill_kernel(const int* __restrict__ row, const int* __restrict__ col,
                            const int* __restrict__ offs, int* __restrict__ cursor,
                            float2* __restrict__ recs,
                            const float* __restrict__ dis, int E) {
    int e = blockIdx.x * blockDim.x + threadIdx.x;
    if (e >= E) return;
    int r = row[e], c = col[e];
    int pos = offs[c] + atomicAdd(&cursor[c], 1);
    recs[pos] = make_float2(__int_as_float(r), dis[r]);
}

// graph boundary offsets from sorted batch; start has G+1 entries
__global__ void graph_bounds(const int* __restrict__ batch, int* __restrict__ start, int n) {
    int i = blockIdx.x * blockDim.x + threadIdx.x;
    if (i >= n) return;
    int b = batch[i];
    if (i == 0) {
        for (int g = 0; g <= b; ++g) start[g] = 0;
    } else {
        int pb = batch[i - 1];
        if (pb != b) for (int g = pb + 1; g <= b; ++g) start[g] = i;
    }
    if (i == n - 1) {
        for (int g = b + 1; g <= N_GRAPHS; ++g) start[g] = n;
    }
}

// ---------------- dense layers ----------------

// h = relu(x @ encW + encb), x: [n,29], W: [29,64]
__global__ void encoder_kernel(const float* __restrict__ x, const float* __restrict__ W,
                               const float* __restrict__ b, float* __restrict__ h, int n) {
    __shared__ float Ws[F_INN * HD];
    __shared__ float bs[HD];
    __shared__ float xs[16 * F_INN];
    int tid = threadIdx.x;
    for (int i = tid; i < F_INN * HD; i += 256) Ws[i] = W[i];
    if (tid < HD) bs[tid] = b[tid];
    int n0 = blockIdx.x * 16;
    for (int i = tid; i < 16 * F_INN; i += 256) {
        int nn = n0 + i / F_INN;
        xs[i] = (nn < n) ? x[(size_t)nn * F_INN + (i % F_INN)] : 0.f;
    }
    __syncthreads();
    #pragma unroll
    for (int it = 0; it < 4; ++it) {
        int l = it * 4 + (tid >> 6);
        int j = tid & 63;
        int nn = n0 + l;
        if (nn < n) {
            float a = bs[j];
            #pragma unroll
            for (int k = 0; k < F_INN; ++k) a = fmaf(xs[l * F_INN + k], Ws[k * HD + j], a);
            h[(size_t)nn * HD + j] = fmaxf(a, 0.f);
        }
    }
}

// Fused GCN layer, barrier-free: agg-then-transform.
// Each wave owns nodes (grid-stride). Gather: 16 edges in flight (4 per quarter-wave).
// Matvec: lane j keeps W column j in 64 VGPRs; agg broadcast via compile-time-lane shfl.
__global__ __launch_bounds__(256, 4)
void layer_kernel(const float* __restrict__ h,
                  const int* __restrict__ offs, const int* __restrict__ cnt,
                  const float2* __restrict__ recs,
                  const float* __restrict__ dis,
                  const float* __restrict__ W, const float* __restrict__ b,
                  float* __restrict__ hout, int n) {
    int lane = threadIdx.x & 63;
    int wave = threadIdx.x >> 6;
    int j = lane;
    float wcol[HD];
    #pragma unroll
    for (int k = 0; k < HD; ++k) wcol[k] = W[k * HD + j];  // coalesced across lanes
    float bb = b[j];
    int q = lane >> 4;        // edge subgroup 0..3
    int f = (lane & 15) * 4;  // feature offset
    int gwave = blockIdx.x * 4 + wave;
    int nwaves = gridDim.x * 4;
    for (int node = gwave; node < n; node += nwaves) {
        float dn = dis[node];
        int s = offs[node];
        int e = s + cnt[node];
        float4 acc = {0.f, 0.f, 0.f, 0.f};
        for (int p = s; p < e; p += 16) {
            int i0 = p + q, i1 = i0 + 4, i2 = i0 + 8, i3 = i0 + 12;
            float2 r0 = recs[min(i0, e - 1)];
            float2 r1 = recs[min(i1, e - 1)];
            float2 r2 = recs[min(i2, e - 1)];
            float2 r3 = recs[min(i3, e - 1)];
            float w0 = (i0 < e) ? r0.y : 0.f;
            float w1 = (i1 < e) ? r1.y : 0.f;
            float w2 = (i2 < e) ? r2.y : 0.f;
            float w3 = (i3 < e) ? r3.y : 0.f;
            const float4 h0 = *reinterpret_cast<const float4*>(&h[(size_t)__float_as_int(r0.x) * HD + f]);
            const float4 h1 = *reinterpret_cast<const float4*>(&h[(size_t)__float_as_int(r1.x) * HD + f]);
            const float4 h2 = *reinterpret_cast<const float4*>(&h[(size_t)__float_as_int(r2.x) * HD + f]);
            const float4 h3 = *reinterpret_cast<const float4*>(&h[(size_t)__float_as_int(r3.x) * HD + f]);
            acc.x = fmaf(w0, h0.x, acc.x);
            acc.y = fmaf(w0, h0.y, acc.y);
            acc.z = fmaf(w0, h0.z, acc.z);
            acc.w = fmaf(w0, h0.w, acc.w);
            acc.x = fmaf(w1, h1.x, acc.x);
            acc.y = fmaf(w1, h1.y, acc.y);
            acc.z = fmaf(w1, h1.z, acc.z);
            acc.w = fmaf(w1, h1.w, acc.w);
            acc.x = fmaf(w2, h2.x, acc.x);
            acc.y = fmaf(w2, h2.y, acc.y);
            acc.z = fmaf(w2, h2.z, acc.z);
            acc.w = fmaf(w2, h2.w, acc.w);
            acc.x = fmaf(w3, h3.x, acc.x);
            acc.y = fmaf(w3, h3.y, acc.y);
            acc.z = fmaf(w3, h3.z, acc.z);
            acc.w = fmaf(w3, h3.w, acc.w);
        }
        // butterfly over edge subgroups: every lane ends with the full row sum
        #pragma unroll
        for (int off = 16; off < 64; off <<= 1) {
            acc.x += __shfl_xor(acc.x, off, 64);
            acc.y += __shfl_xor(acc.y, off, 64);
            acc.z += __shfl_xor(acc.z, off, 64);
            acc.w += __shfl_xor(acc.w, off, 64);
        }
        // self term (all lanes; same 16B per 16-lane class)
        const float4 hv = *reinterpret_cast<const float4*>(&h[(size_t)node * HD + f]);
        acc.x = fmaf(dn, hv.x, acc.x);
        acc.y = fmaf(dn, hv.y, acc.y);
        acc.z = fmaf(dn, hv.z, acc.z);
        acc.w = fmaf(dn, hv.w, acc.w);
        // matvec: out_j = sum_k agg[k] * W[k][j]; agg[k] lives in lane k>>2, comp k&3
        float a0 = 0.f, a1 = 0.f, a2 = 0.f, a3 = 0.f;
        #pragma unroll
        for (int kk = 0; kk < 16; ++kk) {
            a0 = fmaf(__shfl(acc.x, kk, 64), wcol[4 * kk + 0], a0);
            a1 = fmaf(__shfl(acc.y, kk, 64), wcol[4 * kk + 1], a1);
            a2 = fmaf(__shfl(acc.z, kk, 64), wcol[4 * kk + 2], a2);
            a3 = fmaf(__shfl(acc.w, kk, 64), wcol[4 * kk + 3], a3);
        }
        float a = (a0 + a1) + (a2 + a3);
        hout[(size_t)node * HD + j] = fmaxf(fmaf(dn, a, bb), 0.f);
    }
}

// pred_node = h @ nodeW + nodeb, W: [64,6]  (pure streaming, no atomics)
__global__ void node_head(const float* __restrict__ h, const float* __restrict__ W,
                          const float* __restrict__ b, float* __restrict__ out, int n) {
    __shared__ float Ws[HD * NT];
    __shared__ float bs[NT];
    __shared__ float hs[32 * 65];
    int tid = threadIdx.x;
    for (int i = tid; i < HD * NT; i += 256) Ws[i] = W[i];
    if (tid < NT) bs[tid] = b[tid];
    int n0 = blockIdx.x * 32;
    for (int i = tid; i < 32 * HD; i += 256) {
        int nn = n0 + (i >> 6);
        hs[(i >> 6) * 65 + (i & 63)] = (nn < n) ? h[(size_t)n0 * HD + i] : 0.f;
    }
    __syncthreads();
    int l = tid >> 3, t = tid & 7;
    int nn = n0 + l;
    if (nn < n && t < NT) {
        float a = bs[t];
        #pragma unroll
        for (int k = 0; k < HD; ++k) a = fmaf(hs[l * 65 + k], Ws[k * NT + t], a);
        out[(size_t)nn * NT + t] = a;
    }
}

// atomic-free pooling: 4 blocks per graph, each sums a contiguous quarter-range
__global__ void pool_kernel(const float* __restrict__ h, const int* __restrict__ start,
                            float* __restrict__ gpart) {
    __shared__ float red[4][HD];
    int g = blockIdx.x >> 2, q = blockIdx.x & 3;
    int s0 = start[g], e0 = start[g + 1];
    int len = e0 - s0;
    int qs = s0 + (len * q) / 4;
    int qe = s0 + (len * (q + 1)) / 4;
    int wave = threadIdx.x >> 6, lane = threadIdx.x & 63;
    float acc = 0.f;
    for (int r = qs + wave; r < qe; r += 4) acc += h[(size_t)r * HD + lane];
    red[wave][lane] = acc;
    __syncthreads();
    if (wave == 0)
        gpart[(size_t)blockIdx.x * HD + lane] =
            red[0][lane] + red[1][lane] + red[2][lane] + red[3][lane];
}

// gemb = sum(gpart quarters)/count; out = relu(gemb@g1W+g1b)@g2W + g2b
__global__ void global_head(const float* __restrict__ gpart, const int* __restrict__ start,
                            const float* __restrict__ g1W, const float* __restrict__ g1b,
                            const float* __restrict__ g2W, const float* __restrict__ g2b,
                            float* __restrict__ out) {
    __shared__ float rS[HD];
    int g = blockIdx.x;
    int j = threadIdx.x;  // 64
    int cnt = start[g + 1] - start[g];
    float inv = 1.f / fmaxf((float)cnt, 1.f);
    rS[j] = (gpart[(size_t)(4 * g + 0) * HD + j] + gpart[(size_t)(4 * g + 1) * HD + j] +
             gpart[(size_t)(4 * g + 2) * HD + j] + gpart[(size_t)(4 * g + 3) * HD + j]) * inv;
    __syncthreads();
    float a = g1b[j];
    #pragma unroll
    for (int k = 0; k < HD; ++k) a = fmaf(rS[k], g1W[k * HD + j], a);
    a = fmaxf(a, 0.f);
    float o0 = a * g2W[j * GT + 0];
    float o1 = a * g2W[j * GT + 1];
    float o2 = a * g2W[j * GT + 2];
    float o3 = a * g2W[j * GT + 3];
    #pragma unroll
    for (int off = 1; off < 64; off <<= 1) {
        o0 += __shfl_xor(o0, off, 64);
        o1 += __shfl_xor(o1, off, 64);
        o2 += __shfl_xor(o2, off, 64);
        o3 += __shfl_xor(o3, off, 64);
    }
    if (j == 0) {
        out[g * GT + 0] = o0 + g2b[0];
        out[g * GT + 1] = o1 + g2b[1];
        out[g * GT + 2] = o2 + g2b[2];
        out[g * GT + 3] = o3 + g2b[3];
    }
}

// ---------------- launch ----------------

extern "C" void kernel_launch(void* const* d_in, const int* in_sizes, int n_in,
                              void* d_out, int out_size, void* d_ws, size_t ws_size,
                              hipStream_t stream) {
    const float* x    = (const float*)d_in[0];
    const int*   ei   = (const int*)d_in[1];   // [2,E] flat: row=ei[0:E], col=ei[E:2E]
    const int*   batch= (const int*)d_in[2];
    const float* encW = (const float*)d_in[3];
    const float* encb = (const float*)d_in[4];
    const float* convW= (const float*)d_in[5]; // [L,64,64]
    const float* convb= (const float*)d_in[6]; // [L,64]
    const float* nodeW= (const float*)d_in[7];
    const float* nodeb= (const float*)d_in[8];
    const float* g1W  = (const float*)d_in[9];
    const float* g1b  = (const float*)d_in[10];
    const float* g2W  = (const float*)d_in[11];
    const float* g2b  = (const float*)d_in[12];
    float* out = (float*)d_out;

    const int N = N_NODES, E = N_EDGES;

    char* ws = (char*)d_ws;
    size_t off = 0;
    auto alloc = [&](size_t bytes) -> void* {
        void* p = ws + off;
        off += (bytes + 255) & ~(size_t)255;
        return p;
    };
    // zeroed region first (one memset)
    int*   cnt    = (int*)alloc((size_t)N * 4);
    int*   cursor = (int*)alloc((size_t)N * 4);
    size_t zbytes = off;
    // rest
    int*   offs   = (int*)alloc((size_t)N * 4);
    float* dis    = (float*)alloc((size_t)N * 4);
    int*   bsums  = (int*)alloc(256 * 4);
    int*   start  = (int*)alloc((size_t)(N_GRAPHS + 1) * 4);
    float* gpart  = (float*)alloc((size_t)N_GRAPHS * 4 * HD * 4);
    float2* recs  = (float2*)alloc((size_t)E * 8);
    float* h      = (float*)alloc((size_t)N * HD * 4);
    float* h2     = (float*)alloc((size_t)N * HD * 4);

    hipMemsetAsync(d_ws, 0, zbytes, stream);

    const int B = 256;
    // CSR build
    count_edges<<<(E + B - 1) / B, B, 0, stream>>>(ei + E, cnt, E);
    compute_dis<<<(N + B - 1) / B, B, 0, stream>>>(cnt, dis, N);
    int nb1 = (N + 1023) / 1024;
    scan1<<<nb1, 256, 0, stream>>>(cnt, offs, bsums, N);
    scan2<<<1, 256, 0, stream>>>(bsums, nb1);
    scan3<<<(N + B - 1) / B, B, 0, stream>>>(offs, bsums, N);
    fill_kernel<<<(E + B - 1) / B, B, 0, stream>>>(ei, ei + E, offs, cursor, recs, dis, E);
    graph_bounds<<<(N + B - 1) / B, B, 0, stream>>>(batch, start, N);

    // encoder
    encoder_kernel<<<(N + 15) / 16, 256, 0, stream>>>(x, encW, encb, h, N);

    // GCN layers (fused aggregate + transform), ping-pong h <-> h2
    float* hin = h;
    float* hot = h2;
    for (int i = 0; i < NLAYERS; ++i) {
        layer_kernel<<<1280, 256, 0, stream>>>(hin, offs, cnt, recs, dis,
                                               convW + (size_t)i * HD * HD,
                                               convb + (size_t)i * HD, hot, N);
        float* t = hin; hin = hot; hot = t;
    }

    // heads
    node_head<<<(N + 31) / 32, 256, 0, stream>>>(hin, nodeW, nodeb, out, N);
    pool_kernel<<<N_GRAPHS * 4, 256, 0, stream>>>(hin, start, gpart);
    global_head<<<N_GRAPHS, 64, 0, stream>>>(gpart, start, g1W, g1b, g2W, g2b, out + (size_t)N * NT);
}

// Round 5
// 477.171 us; speedup vs baseline: 1.2757x; 1.2757x over previous
//
#include <hip/hip_runtime.h>

#define N_NODES 100000
#define N_EDGES 1250000
#define N_GRAPHS 64
#define F_INN 29
#define HD 64
#define NT 6
#define GT 4
#define NLAYERS 4

// ---------------- CSR construction ----------------

__global__ void count_edges(const int* __restrict__ col, int* __restrict__ cnt, int E) {
    int e = blockIdx.x * blockDim.x + threadIdx.x;
    if (e < E) atomicAdd(&cnt[col[e]], 1);
}

__global__ void compute_dis(const int* __restrict__ cnt, float* __restrict__ dis, int n) {
    int i = blockIdx.x * blockDim.x + threadIdx.x;
    if (i < n) dis[i] = rsqrtf((float)(cnt[i] + 1));  // +1 self loop; always > 0
}

// exclusive scan, 3-kernel hierarchy. scan1: 1024 elems/block (4/thread, block=256)
__global__ void scan1(const int* __restrict__ in, int* __restrict__ out,
                      int* __restrict__ bsums, int n) {
    __shared__ int wsum[4];
    int tid = threadIdx.x;
    int base = blockIdx.x * 1024 + tid * 4;
    int v0 = (base + 0 < n) ? in[base + 0] : 0;
    int v1 = (base + 1 < n) ? in[base + 1] : 0;
    int v2 = (base + 2 < n) ? in[base + 2] : 0;
    int v3 = (base + 3 < n) ? in[base + 3] : 0;
    int tsum = v0 + v1 + v2 + v3;
    int incl = tsum;
    int lane = tid & 63;
    #pragma unroll
    for (int off = 1; off < 64; off <<= 1) {
        int t = __shfl_up(incl, (unsigned)off, 64);
        if (lane >= off) incl += t;
    }
    if (lane == 63) wsum[tid >> 6] = incl;
    __syncthreads();
    int woff = 0;
    for (int w = 0; w < (tid >> 6); ++w) woff += wsum[w];
    int run = woff + incl - tsum;  // exclusive prefix of this thread's first elem
    if (base + 0 < n) out[base + 0] = run; run += v0;
    if (base + 1 < n) out[base + 1] = run; run += v1;
    if (base + 2 < n) out[base + 2] = run; run += v2;
    if (base + 3 < n) out[base + 3] = run;
    if (tid == 255) bsums[blockIdx.x] = woff + incl;  // block total
}

__global__ void scan2(int* __restrict__ bsums, int nb) {
    __shared__ int s[256];
    int tid = threadIdx.x;
    int v = (tid < nb) ? bsums[tid] : 0;
    s[tid] = v;
    __syncthreads();
    #pragma unroll
    for (int off = 1; off < 256; off <<= 1) {
        int t = (tid >= off) ? s[tid - off] : 0;
        __syncthreads();
        s[tid] += t;
        __syncthreads();
    }
    if (tid < nb) bsums[tid] = s[tid] - v;  // exclusive, in place
}

__global__ void scan3(int* __restrict__ out, const int* __restrict__ bsums, int n) {
    int i = blockIdx.x * blockDim.x + threadIdx.x;
    if (i < n) out[i] += bsums[i >> 10];
}

// packed edge record: {src index (bit-cast), dis[src]}
__global__ void fill_kernel(const int* __restrict__ row, const int* __restrict__ col,
                            const int* __restrict__ offs, int* __restrict__ cursor,
                            float2* __restrict__ recs,
                            const float* __restrict__ dis, int E) {
    int e = blockIdx.x * blockDim.x + threadIdx.x;
    if (e >= E) return;
    int r = row[e], c = col[e];
    int pos = offs[c] + atomicAdd(&cursor[c], 1);
    recs[pos] = make_float2(__int_as_float(r), dis[r]);
}

// graph boundary offsets from sorted batch; start has G+1 entries
__global__ void graph_bounds(const int* __restrict__ batch, int* __restrict__ start, int n) {
    int i = blockIdx.x * blockDim.x + threadIdx.x;
    if (i >= n) return;
    int b = batch[i];
    if (i == 0) {
        for (int g = 0; g <= b; ++g) start[g] = 0;
    } else {
        int pb = batch[i - 1];
        if (pb != b) for (int g = pb + 1; g <= b; ++g) start[g] = i;
    }
    if (i == n - 1) {
        for (int g = b + 1; g <= N_GRAPHS; ++g) start[g] = n;
    }
}

// ---------------- dense layers ----------------

// h = relu(x @ encW + encb), x: [n,29], W: [29,64]
__global__ void encoder_kernel(const float* __restrict__ x, const float* __restrict__ W,
                               const float* __restrict__ b, float* __restrict__ h, int n) {
    __shared__ float Ws[F_INN * HD];
    __shared__ float bs[HD];
    __shared__ float xs[16 * F_INN];
    int tid = threadIdx.x;
    for (int i = tid; i < F_INN * HD; i += 256) Ws[i] = W[i];
    if (tid < HD) bs[tid] = b[tid];
    int n0 = blockIdx.x * 16;
    for (int i = tid; i < 16 * F_INN; i += 256) {
        int nn = n0 + i / F_INN;
        xs[i] = (nn < n) ? x[(size_t)nn * F_INN + (i % F_INN)] : 0.f;
    }
    __syncthreads();
    #pragma unroll
    for (int it = 0; it < 4; ++it) {
        int l = it * 4 + (tid >> 6);
        int j = tid & 63;
        int nn = n0 + l;
        if (nn < n) {
            float a = bs[j];
            #pragma unroll
            for (int k = 0; k < F_INN; ++k) a = fmaf(xs[l * F_INN + k], Ws[k * HD + j], a);
            h[(size_t)nn * HD + j] = fmaxf(a, 0.f);
        }
    }
}

// Fused GCN layer: persistent blocks, W staged in LDS once per block (one barrier),
// then each wave grid-strides over nodes independently (no in-loop barriers).
// Gather: 16 edges in flight (4 per quarter-wave). Agg->matvec broadcast via
// per-wave LDS slot (wave-local, compiler lgkmcnt wait, no barrier needed).
__global__ void layer_kernel(const float* __restrict__ h,
                             const int* __restrict__ offs, const int* __restrict__ cnt,
                             const float2* __restrict__ recs,
                             const float* __restrict__ dis,
                             const float* __restrict__ W, const float* __restrict__ b,
                             float* __restrict__ hout, int n) {
    __shared__ float Ws[HD * HD];
    __shared__ float bs[HD];
    __shared__ float accS[4][HD];
    int tid = threadIdx.x;
    for (int i = tid; i < HD * HD; i += 256) Ws[i] = W[i];
    if (tid < HD) bs[tid] = b[tid];
    __syncthreads();  // the only barrier: Ws/bs staged
    int wave = tid >> 6;
    int lane = tid & 63;
    int j = lane;
    float bb = bs[j];
    int q = lane >> 4;        // edge subgroup 0..3
    int f = (lane & 15) * 4;  // feature offset
    int gwave = blockIdx.x * 4 + wave;
    int nwaves = gridDim.x * 4;
    float* myAcc = accS[wave];
    for (int node = gwave; node < n; node += nwaves) {
        float dn = dis[node];
        int s = offs[node];
        int e = s + cnt[node];
        float4 acc = {0.f, 0.f, 0.f, 0.f};
        for (int p = s; p < e; p += 16) {
            int i0 = p + q, i1 = i0 + 4, i2 = i0 + 8, i3 = i0 + 12;
            float2 r0 = recs[min(i0, e - 1)];
            float2 r1 = recs[min(i1, e - 1)];
            float2 r2 = recs[min(i2, e - 1)];
            float2 r3 = recs[min(i3, e - 1)];
            float w0 = (i0 < e) ? r0.y : 0.f;
            float w1 = (i1 < e) ? r1.y : 0.f;
            float w2 = (i2 < e) ? r2.y : 0.f;
            float w3 = (i3 < e) ? r3.y : 0.f;
            const float4 h0 = *reinterpret_cast<const float4*>(&h[(size_t)__float_as_int(r0.x) * HD + f]);
            const float4 h1 = *reinterpret_cast<const float4*>(&h[(size_t)__float_as_int(r1.x) * HD + f]);
            const float4 h2 = *reinterpret_cast<const float4*>(&h[(size_t)__float_as_int(r2.x) * HD + f]);
            const float4 h3 = *reinterpret_cast<const float4*>(&h[(size_t)__float_as_int(r3.x) * HD + f]);
            acc.x = fmaf(w0, h0.x, acc.x);
            acc.y = fmaf(w0, h0.y, acc.y);
            acc.z = fmaf(w0, h0.z, acc.z);
            acc.w = fmaf(w0, h0.w, acc.w);
            acc.x = fmaf(w1, h1.x, acc.x);
            acc.y = fmaf(w1, h1.y, acc.y);
            acc.z = fmaf(w1, h1.z, acc.z);
            acc.w = fmaf(w1, h1.w, acc.w);
            acc.x = fmaf(w2, h2.x, acc.x);
            acc.y = fmaf(w2, h2.y, acc.y);
            acc.z = fmaf(w2, h2.z, acc.z);
            acc.w = fmaf(w2, h2.w, acc.w);
            acc.x = fmaf(w3, h3.x, acc.x);
            acc.y = fmaf(w3, h3.y, acc.y);
            acc.z = fmaf(w3, h3.z, acc.z);
            acc.w = fmaf(w3, h3.w, acc.w);
        }
        // butterfly over edge subgroups (bits 4,5): all lanes get the row sum
        #pragma unroll
        for (int off = 16; off < 64; off <<= 1) {
            acc.x += __shfl_xor(acc.x, off, 64);
            acc.y += __shfl_xor(acc.y, off, 64);
            acc.z += __shfl_xor(acc.z, off, 64);
            acc.w += __shfl_xor(acc.w, off, 64);
        }
        // self term
        const float4 hv = *reinterpret_cast<const float4*>(&h[(size_t)node * HD + f]);
        acc.x = fmaf(dn, hv.x, acc.x);
        acc.y = fmaf(dn, hv.y, acc.y);
        acc.z = fmaf(dn, hv.z, acc.z);
        acc.w = fmaf(dn, hv.w, acc.w);
        // stash agg row in this wave's LDS slot (lanes 0..15 cover all 64 feats)
        if (q == 0) *reinterpret_cast<float4*>(&myAcc[f]) = acc;
        // matvec: out_j = sum_k agg[k] * W[k][j]  (wave-local LDS, no barrier)
        float a0 = 0.f, a1 = 0.f, a2 = 0.f, a3 = 0.f;
        #pragma unroll
        for (int kk = 0; kk < 16; ++kk) {
            const float4 ag = *reinterpret_cast<const float4*>(&myAcc[kk * 4]);
            a0 = fmaf(ag.x, Ws[(4 * kk + 0) * HD + j], a0);
            a1 = fmaf(ag.y, Ws[(4 * kk + 1) * HD + j], a1);
            a2 = fmaf(ag.z, Ws[(4 * kk + 2) * HD + j], a2);
            a3 = fmaf(ag.w, Ws[(4 * kk + 3) * HD + j], a3);
        }
        float a = (a0 + a1) + (a2 + a3);
        hout[(size_t)node * HD + j] = fmaxf(fmaf(dn, a, bb), 0.f);
    }
}

// pred_node = h @ nodeW + nodeb, W: [64,6]  (pure streaming, no atomics)
__global__ void node_head(const float* __restrict__ h, const float* __restrict__ W,
                          const float* __restrict__ b, float* __restrict__ out, int n) {
    __shared__ float Ws[HD * NT];
    __shared__ float bs[NT];
    __shared__ float hs[32 * 65];
    int tid = threadIdx.x;
    for (int i = tid; i < HD * NT; i += 256) Ws[i] = W[i];
    if (tid < NT) bs[tid] = b[tid];
    int n0 = blockIdx.x * 32;
    for (int i = tid; i < 32 * HD; i += 256) {
        int nn = n0 + (i >> 6);
        hs[(i >> 6) * 65 + (i & 63)] = (nn < n) ? h[(size_t)n0 * HD + i] : 0.f;
    }
    __syncthreads();
    int l = tid >> 3, t = tid & 7;
    int nn = n0 + l;
    if (nn < n && t < NT) {
        float a = bs[t];
        #pragma unroll
        for (int k = 0; k < HD; ++k) a = fmaf(hs[l * 65 + k], Ws[k * NT + t], a);
        out[(size_t)nn * NT + t] = a;
    }
}

// atomic-free pooling: 4 blocks per graph, each sums a contiguous quarter-range
__global__ void pool_kernel(const float* __restrict__ h, const int* __restrict__ start,
                            float* __restrict__ gpart) {
    __shared__ float red[4][HD];
    int g = blockIdx.x >> 2, q = blockIdx.x & 3;
    int s0 = start[g], e0 = start[g + 1];
    int len = e0 - s0;
    int qs = s0 + (len * q) / 4;
    int qe = s0 + (len * (q + 1)) / 4;
    int wave = threadIdx.x >> 6, lane = threadIdx.x & 63;
    float acc = 0.f;
    for (int r = qs + wave; r < qe; r += 4) acc += h[(size_t)r * HD + lane];
    red[wave][lane] = acc;
    __syncthreads();
    if (wave == 0)
        gpart[(size_t)blockIdx.x * HD + lane] =
            red[0][lane] + red[1][lane] + red[2][lane] + red[3][lane];
}

// gemb = sum(gpart quarters)/count; out = relu(gemb@g1W+g1b)@g2W + g2b
__global__ void global_head(const float* __restrict__ gpart, const int* __restrict__ start,
                            const float* __restrict__ g1W, const float* __restrict__ g1b,
                            const float* __restrict__ g2W, const float* __restrict__ g2b,
                            float* __restrict__ out) {
    __shared__ float rS[HD];
    int g = blockIdx.x;
    int j = threadIdx.x;  // 64
    int cnt = start[g + 1] - start[g];
    float inv = 1.f / fmaxf((float)cnt, 1.f);
    rS[j] = (gpart[(size_t)(4 * g + 0) * HD + j] + gpart[(size_t)(4 * g + 1) * HD + j] +
             gpart[(size_t)(4 * g + 2) * HD + j] + gpart[(size_t)(4 * g + 3) * HD + j]) * inv;
    __syncthreads();
    float a = g1b[j];
    #pragma unroll
    for (int k = 0; k < HD; ++k) a = fmaf(rS[k], g1W[k * HD + j], a);
    a = fmaxf(a, 0.f);
    float o0 = a * g2W[j * GT + 0];
    float o1 = a * g2W[j * GT + 1];
    float o2 = a * g2W[j * GT + 2];
    float o3 = a * g2W[j * GT + 3];
    #pragma unroll
    for (int off = 1; off < 64; off <<= 1) {
        o0 += __shfl_xor(o0, off, 64);
        o1 += __shfl_xor(o1, off, 64);
        o2 += __shfl_xor(o2, off, 64);
        o3 += __shfl_xor(o3, off, 64);
    }
    if (j == 0) {
        out[g * GT + 0] = o0 + g2b[0];
        out[g * GT + 1] = o1 + g2b[1];
        out[g * GT + 2] = o2 + g2b[2];
        out[g * GT + 3] = o3 + g2b[3];
    }
}

// ---------------- launch ----------------

extern "C" void kernel_launch(void* const* d_in, const int* in_sizes, int n_in,
                              void* d_out, int out_size, void* d_ws, size_t ws_size,
                              hipStream_t stream) {
    const float* x    = (const float*)d_in[0];
    const int*   ei   = (const int*)d_in[1];   // [2,E] flat: row=ei[0:E], col=ei[E:2E]
    const int*   batch= (const int*)d_in[2];
    const float* encW = (const float*)d_in[3];
    const float* encb = (const float*)d_in[4];
    const float* convW= (const float*)d_in[5]; // [L,64,64]
    const float* convb= (const float*)d_in[6]; // [L,64]
    const float* nodeW= (const float*)d_in[7];
    const float* nodeb= (const float*)d_in[8];
    const float* g1W  = (const float*)d_in[9];
    const float* g1b  = (const float*)d_in[10];
    const float* g2W  = (const float*)d_in[11];
    const float* g2b  = (const float*)d_in[12];
    float* out = (float*)d_out;

    const int N = N_NODES, E = N_EDGES;

    char* ws = (char*)d_ws;
    size_t off = 0;
    auto alloc = [&](size_t bytes) -> void* {
        void* p = ws + off;
        off += (bytes + 255) & ~(size_t)255;
        return p;
    };
    // zeroed region first (one memset)
    int*   cnt    = (int*)alloc((size_t)N * 4);
    int*   cursor = (int*)alloc((size_t)N * 4);
    size_t zbytes = off;
    // rest
    int*   offs   = (int*)alloc((size_t)N * 4);
    float* dis    = (float*)alloc((size_t)N * 4);
    int*   bsums  = (int*)alloc(256 * 4);
    int*   start  = (int*)alloc((size_t)(N_GRAPHS + 1) * 4);
    float* gpart  = (float*)alloc((size_t)N_GRAPHS * 4 * HD * 4);
    float2* recs  = (float2*)alloc((size_t)E * 8);
    float* h      = (float*)alloc((size_t)N * HD * 4);
    float* h2     = (float*)alloc((size_t)N * HD * 4);

    hipMemsetAsync(d_ws, 0, zbytes, stream);

    const int B = 256;
    // CSR build
    count_edges<<<(E + B - 1) / B, B, 0, stream>>>(ei + E, cnt, E);
    compute_dis<<<(N + B - 1) / B, B, 0, stream>>>(cnt, dis, N);
    int nb1 = (N + 1023) / 1024;
    scan1<<<nb1, 256, 0, stream>>>(cnt, offs, bsums, N);
    scan2<<<1, 256, 0, stream>>>(bsums, nb1);
    scan3<<<(N + B - 1) / B, B, 0, stream>>>(offs, bsums, N);
    fill_kernel<<<(E + B - 1) / B, B, 0, stream>>>(ei, ei + E, offs, cursor, recs, dis, E);
    graph_bounds<<<(N + B - 1) / B, B, 0, stream>>>(batch, start, N);

    // encoder
    encoder_kernel<<<(N + 15) / 16, 256, 0, stream>>>(x, encW, encb, h, N);

    // GCN layers (fused aggregate + transform), ping-pong h <-> h2
    float* hin = h;
    float* hot = h2;
    for (int i = 0; i < NLAYERS; ++i) {
        layer_kernel<<<2048, 256, 0, stream>>>(hin, offs, cnt, recs, dis,
                                               convW + (size_t)i * HD * HD,
                                               convb + (size_t)i * HD, hot, N);
        float* t = hin; hin = hot; hot = t;
    }

    // heads
    node_head<<<(N + 31) / 32, 256, 0, stream>>>(hin, nodeW, nodeb, out, N);
    pool_kernel<<<N_GRAPHS * 4, 256, 0, stream>>>(hin, start, gpart);
    global_head<<<N_GRAPHS, 64, 0, stream>>>(gpart, start, g1W, g1b, g2W, g2b, out + (size_t)N * NT);
}